// Round 1
// baseline (75481.720 us; speedup 1.0000x reference)
//
#include <hip/hip_runtime.h>

// CustomRNN (GRU, SEQ=2048, B=256, D=512) + FC(1000) + log_softmax over batch axis.
//
// Plan:
//   prep_kernel : cast U->UT bf16 [3][512 n][512 k], W->WT bf16 [1536 n][512 k], fold biases
//   gate_gemm   : gates[t,b,1536] = x[t,b,:] @ [Wz|Wr|Wh] + (b+bu)   (bf16 MFMA, chunked by ws)
//   gru_rec     : persistent kernel, 256 blocks = 16 groups x 16 col-slice blocks.
//                 U slices live in REGISTERS (24 x bf16x8 per thread). h broadcast per group
//                 through global bf16 buffer (L2-local), 2 device-scope group barriers/step.
//   fc_kernel   : logits = relu(h_final) @ Wfc + bfc
//   lsm_kernel  : log_softmax over the 256-batch axis per class column.

typedef unsigned short ushort_t;
typedef unsigned int uint_t;
typedef __bf16 bf16_t;
typedef bf16_t bf16x8 __attribute__((ext_vector_type(8)));
typedef float f32x4 __attribute__((ext_vector_type(4)));

__device__ __forceinline__ ushort_t f2bf(float f) {
  uint_t u = __float_as_uint(f);
  u += 0x7FFFu + ((u >> 16) & 1u);   // round-to-nearest-even
  return (ushort_t)(u >> 16);
}
__device__ __forceinline__ float bf2f(ushort_t h) {
  return __uint_as_float(((uint_t)h) << 16);
}

// ---------------------------------------------------------------- prep
__global__ __launch_bounds__(256) void prep_kernel(
    const float* __restrict__ Wz, const float* __restrict__ Wr, const float* __restrict__ Wh,
    const float* __restrict__ Uz, const float* __restrict__ Ur, const float* __restrict__ Uh,
    const float* __restrict__ bz, const float* __restrict__ buz,
    const float* __restrict__ br, const float* __restrict__ bur,
    const float* __restrict__ bh, const float* __restrict__ buh,
    ushort_t* __restrict__ UT, ushort_t* __restrict__ WT, float* __restrict__ gbias)
{
  const int idx = blockIdx.x * 256 + threadIdx.x;  // exactly 786432 threads
  {
    const int gate = idx >> 18, n = (idx >> 9) & 511, k = idx & 511;
    const float* U = (gate == 0) ? Uz : (gate == 1 ? Ur : Uh);
    UT[idx] = f2bf(U[k * 512 + n]);                 // UT[gate][n][k] = U[k][n]
  }
  {
    const int n = idx >> 9, k = idx & 511;
    const int gate = n >> 9, nn = n & 511;
    const float* W = (gate == 0) ? Wz : (gate == 1 ? Wr : Wh);
    WT[idx] = f2bf(W[k * 512 + nn]);                // WT[n][k] = W[k][n]
  }
  if (idx < 1536) {
    const int gate = idx >> 9, nn = idx & 511;
    gbias[idx] = (gate == 0) ? (bz[nn] + buz[nn])
               : (gate == 1) ? (br[nn] + bur[nn])
                             : (bh[nn] + buh[nn]);
  }
}

// ---------------------------------------------------------------- gate GEMM
// C[M,1536] = x[M,512] @ Wcat + gbias, bf16 out. BM=BN=128, BK=64, 256 thr (4 waves, 64x64 each).
__global__ __launch_bounds__(256) void gate_gemm(
    const float* __restrict__ x,
    const ushort_t* __restrict__ WT,     // [1536][512] (n-major)
    const float* __restrict__ gbias,
    ushort_t* __restrict__ gout,         // [M][1536]
    int mtiles)
{
  __shared__ ushort_t A_sh[128 * 72];    // +8 pad breaks bank conflicts
  __shared__ ushort_t B_sh[128 * 72];
  const int bid = blockIdx.x;
  int mt, nt;
  if ((mtiles & 31) == 0) {              // supertile 32 mtiles x 12 ntiles for A L2/L3 reuse
    const int sb = bid / 384;
    const int r = bid - sb * 384;
    mt = sb * 32 + (r & 31);
    nt = r >> 5;
  } else {
    mt = bid / 12;
    nt = bid - mt * 12;
  }
  const int mrow0 = mt * 128;
  const int ncol0 = nt * 128;
  const int tid = threadIdx.x;
  const int wid = tid >> 6;
  const int lane = tid & 63;
  const int wm = wid >> 1, wn = wid & 1;
  const int l15 = lane & 15, l4 = lane >> 4;

  const f32x4 vzero = {0.f, 0.f, 0.f, 0.f};
  f32x4 acc[4][4];
#pragma unroll
  for (int m = 0; m < 4; ++m) {
#pragma unroll
    for (int n = 0; n < 4; ++n) acc[m][n] = vzero;
  }

  const int ar = tid >> 4;   // A: row group (16 rows/pass)
  const int ak = tid & 15;   // A: float4 slot along K
  const int bn = tid >> 3;   // B: n-row group (32/pass)
  const int bk = tid & 7;    // B: uint4 slot along K

  for (int ks = 0; ks < 8; ++ks) {
    if (ks) __syncthreads();
    const int k0 = ks * 64;
#pragma unroll
    for (int p = 0; p < 8; ++p) {
      const int r = p * 16 + ar;
      const float4 v = *(const float4*)&x[(size_t)(mrow0 + r) * 512 + (k0 + ak * 4)];
      ushort4 hv;
      hv.x = f2bf(v.x); hv.y = f2bf(v.y); hv.z = f2bf(v.z); hv.w = f2bf(v.w);
      *(ushort4*)&A_sh[r * 72 + ak * 4] = hv;
    }
#pragma unroll
    for (int p = 0; p < 4; ++p) {
      const int n = p * 32 + bn;
      *(uint4*)&B_sh[n * 72 + bk * 8] =
          *(const uint4*)&WT[(size_t)(ncol0 + n) * 512 + (k0 + bk * 8)];
    }
    __syncthreads();
#pragma unroll
    for (int kk = 0; kk < 2; ++kk) {
      bf16x8 a[4], b[4];
#pragma unroll
      for (int m = 0; m < 4; ++m)
        a[m] = *(const bf16x8*)&A_sh[(wm * 64 + m * 16 + l15) * 72 + kk * 32 + l4 * 8];
#pragma unroll
      for (int n = 0; n < 4; ++n)
        b[n] = *(const bf16x8*)&B_sh[(wn * 64 + n * 16 + l15) * 72 + kk * 32 + l4 * 8];
#pragma unroll
      for (int m = 0; m < 4; ++m) {
#pragma unroll
        for (int n = 0; n < 4; ++n)
          acc[m][n] = __builtin_amdgcn_mfma_f32_16x16x32_bf16(a[m], b[n], acc[m][n], 0, 0, 0);
      }
    }
  }
#pragma unroll
  for (int n = 0; n < 4; ++n) {
    const int gcol = ncol0 + wn * 64 + n * 16 + l15;
    const float bv = gbias[gcol];
#pragma unroll
    for (int m = 0; m < 4; ++m) {
      const int grow = mrow0 + wm * 64 + m * 16 + l4 * 4;
#pragma unroll
      for (int q = 0; q < 4; ++q)
        gout[(size_t)(grow + q) * 1536 + gcol] = f2bf(acc[m][n][q] + bv);
    }
  }
}

// ---------------------------------------------------------------- group barrier (16 blocks)
__device__ __forceinline__ void group_barrier(uint_t* arrive, uint_t* gen, uint_t target) {
  __syncthreads();
  if (threadIdx.x == 0) {
    __threadfence();  // agent-scope release of this block's prior global writes
    const uint_t a = __hip_atomic_fetch_add(arrive, 1u, __ATOMIC_ACQ_REL, __HIP_MEMORY_SCOPE_AGENT);
    if (a == 15u) {
      __hip_atomic_store(arrive, 0u, __ATOMIC_RELAXED, __HIP_MEMORY_SCOPE_AGENT);
      __hip_atomic_store(gen, target, __ATOMIC_RELEASE, __HIP_MEMORY_SCOPE_AGENT);
    } else {
      int cnt = 0;
      while (__hip_atomic_load(gen, __ATOMIC_ACQUIRE, __HIP_MEMORY_SCOPE_AGENT) < target) {
        __builtin_amdgcn_s_sleep(8);
        if (++cnt > (1 << 20)) break;  // safety bailout: avoid infinite hang
      }
    }
  }
  __syncthreads();
}

// ---------------------------------------------------------------- persistent GRU recurrence
// grid = 256 blocks x 256 thr. group g = bid&15 (16 blocks, same XCD under round-robin),
// slice j = bid>>4 owns columns j*32..j*32+31 of each gate. batch rows = g*16..g*16+15.
__global__ __launch_bounds__(256, 1) void gru_rec(
    const ushort_t* __restrict__ UT,     // [3][512 n][512 k] bf16
    const ushort_t* __restrict__ gates,  // [Tc][256][1536] bf16 (chunk-local)
    ushort_t* __restrict__ h_buf,        // [256][512] bf16
    ushort_t* __restrict__ rh_buf,       // [256][512] bf16
    float* __restrict__ h_state,         // [256][512] fp32 (chunk carry + final)
    uint_t* __restrict__ bars,
    int Tc, int first)
{
  __shared__ ushort_t h_st[16 * 520];    // staged h / rh tile, +8 pad
  __shared__ float z_sh[512];            // z [16 rows][32 cols]
  __shared__ float hown[512];            // fp32 own h slice [16][32]
  __shared__ float red[512];             // phase-2 K-split reduction [2][16][16]

  const int tid = threadIdx.x;
  const int bid = blockIdx.x;
  const int g = bid & 15;
  const int j = bid >> 4;
  const int wid = tid >> 6;
  const int lane = tid & 63;
  const int l15 = lane & 15;
  const int l4 = lane >> 4;

  uint_t* bar_arr = bars + g * 32;
  uint_t* bar_gen = bar_arr + 16;
  uint_t mygen = 0;

  const int p1gate = wid >> 1;  // phase1: waves 0,1 -> z ; waves 2,3 -> r
  const int p1nt = wid & 1;     // 16-col subtile
  const int p2nt = wid >> 1;    // phase2 subtile
  const int p2kh = wid & 1;     // phase2 K half

  // U fragments persistent in registers (B-operand, col = l15, k-contig 8)
  bf16x8 UB[16];
  {
    const size_t base = (size_t)((p1gate << 9) + j * 32 + p1nt * 16 + l15) * 512 + (size_t)(l4 * 8);
#pragma unroll
    for (int kk = 0; kk < 16; ++kk) UB[kk] = *(const bf16x8*)&UT[base + (size_t)kk * 32];
  }
  bf16x8 UH[8];
  {
    const size_t base = (size_t)(1024 + j * 32 + p2nt * 16 + l15) * 512 + (size_t)(p2kh * 256 + l4 * 8);
#pragma unroll
    for (int kk = 0; kk < 8; ++kk) UH[kk] = *(const bf16x8*)&UT[base + (size_t)kk * 32];
  }

  if (first) {
    for (int i = tid; i < 512; i += 256) {
      const int r = i >> 5, c = i & 31;
      h_buf[((g * 16 + r) << 9) + j * 32 + c] = 0;
      hown[i] = 0.f;
    }
  } else {
    for (int i = tid; i < 512; i += 256) {
      const int r = i >> 5, c = i & 31;
      hown[i] = h_state[((g * 16 + r) << 9) + j * 32 + c];
    }
  }
  group_barrier(bar_arr, bar_gen, ++mygen);

  for (int tt = 0; tt < Tc; ++tt) {
    // gate prefetch (independent of h -> issues early, hides HBM latency)
    float gp1[4], gp2[4];
    {
      const size_t gb = (size_t)((size_t)tt * 256 + g * 16) * 1536;
      const int colg1 = j * 32 + p1nt * 16 + l15;
      const int colg2 = j * 32 + p2nt * 16 + l15;
#pragma unroll
      for (int q = 0; q < 4; ++q) {
        gp1[q] = bf2f(gates[gb + (size_t)(l4 * 4 + q) * 1536 + (p1gate << 9) + colg1]);
        gp2[q] = bf2f(gates[gb + (size_t)(l4 * 4 + q) * 1536 + 1024 + colg2]);
      }
    }
    // ---- phase 1: z, r from h
    for (int i = tid; i < 1024; i += 256) {
      const int r = i >> 6, kc = i & 63;
      *(uint4*)&h_st[r * 520 + kc * 8] = *(const uint4*)&h_buf[((g * 16 + r) << 9) + kc * 8];
    }
    __syncthreads();
    {
      const ushort_t* ap = &h_st[l15 * 520 + l4 * 8];
      f32x4 a0 = {0.f, 0.f, 0.f, 0.f}, a1 = {0.f, 0.f, 0.f, 0.f};
#pragma unroll
      for (int kk = 0; kk < 16; kk += 2) {
        a0 = __builtin_amdgcn_mfma_f32_16x16x32_bf16(*(const bf16x8*)(ap + kk * 32), UB[kk], a0, 0, 0, 0);
        a1 = __builtin_amdgcn_mfma_f32_16x16x32_bf16(*(const bf16x8*)(ap + kk * 32 + 32), UB[kk + 1], a1, 0, 0, 0);
      }
      const f32x4 acc = a0 + a1;
      const int lc = p1nt * 16 + l15;
      const int colg = j * 32 + lc;
#pragma unroll
      for (int q = 0; q < 4; ++q) {
        const int row = l4 * 4 + q;
        const float pre = acc[q] + gp1[q];
        const float s = 1.f / (1.f + __expf(-pre));
        if (p1gate == 0) z_sh[row * 32 + lc] = s;
        else rh_buf[((g * 16 + row) << 9) + colg] = f2bf(s * hown[row * 32 + lc]);
      }
    }
    group_barrier(bar_arr, bar_gen, ++mygen);
    // ---- phase 2: h~ from (r*h), h update
    for (int i = tid; i < 1024; i += 256) {
      const int r = i >> 6, kc = i & 63;
      *(uint4*)&h_st[r * 520 + kc * 8] = *(const uint4*)&rh_buf[((g * 16 + r) << 9) + kc * 8];
    }
    __syncthreads();
    {
      const ushort_t* ap = &h_st[l15 * 520 + p2kh * 256 + l4 * 8];
      f32x4 a0 = {0.f, 0.f, 0.f, 0.f}, a1 = {0.f, 0.f, 0.f, 0.f};
#pragma unroll
      for (int kk = 0; kk < 8; kk += 2) {
        a0 = __builtin_amdgcn_mfma_f32_16x16x32_bf16(*(const bf16x8*)(ap + kk * 32), UH[kk], a0, 0, 0, 0);
        a1 = __builtin_amdgcn_mfma_f32_16x16x32_bf16(*(const bf16x8*)(ap + kk * 32 + 32), UH[kk + 1], a1, 0, 0, 0);
      }
      const f32x4 acc = a0 + a1;
      if (p2kh == 1) {
#pragma unroll
        for (int q = 0; q < 4; ++q) red[p2nt * 256 + (l4 * 4 + q) * 16 + l15] = acc[q];
      }
      __syncthreads();
      if (p2kh == 0) {
        const int lc = p2nt * 16 + l15;
        const int colg = j * 32 + lc;
#pragma unroll
        for (int q = 0; q < 4; ++q) {
          const int row = l4 * 4 + q;
          const float dot = acc[q] + red[p2nt * 256 + row * 16 + l15];
          float pre = dot + gp2[q];
          pre = fminf(15.f, fmaxf(-15.f, pre));
          const float e = __expf(2.f * pre);
          const float th = (e - 1.f) / (e + 1.f);
          const float z = z_sh[row * 32 + lc];
          const float hold = hown[row * 32 + lc];
          const float hnew = (1.f - z) * hold + z * th;
          hown[row * 32 + lc] = hnew;
          h_buf[((g * 16 + row) << 9) + colg] = f2bf(hnew);
          if (tt == Tc - 1) h_state[((g * 16 + row) << 9) + colg] = hnew;
        }
      }
    }
    group_barrier(bar_arr, bar_gen, ++mygen);
  }
}

// ---------------------------------------------------------------- FC: logits = relu(h) @ Wfc + bfc
__global__ __launch_bounds__(256) void fc_kernel(
    const float* __restrict__ h, const float* __restrict__ Wfc,
    const float* __restrict__ bfc, float* __restrict__ logits)
{
  __shared__ float hsh[16][520];
  const int tid = threadIdx.x;
  const int by = blockIdx.y;
  {
    const int r = tid >> 4, seg = tid & 15;
    const float* src = &h[(size_t)(by * 16 + r) * 512 + seg * 32];
#pragma unroll
    for (int i = 0; i < 8; ++i) {
      float4 v = *(const float4*)&src[i * 4];
      v.x = fmaxf(v.x, 0.f); v.y = fmaxf(v.y, 0.f);
      v.z = fmaxf(v.z, 0.f); v.w = fmaxf(v.w, 0.f);
      *(float4*)&hsh[r][seg * 32 + i * 4] = v;
    }
  }
  __syncthreads();
  const int c = tid & 63, rq = tid >> 6;
  const int gc = blockIdx.x * 64 + c;
  if (gc >= 1000) return;
  float acc0 = 0.f, acc1 = 0.f, acc2 = 0.f, acc3 = 0.f;
  for (int k = 0; k < 512; ++k) {
    const float w = Wfc[(size_t)k * 1000 + gc];
    acc0 += hsh[rq * 4 + 0][k] * w;
    acc1 += hsh[rq * 4 + 1][k] * w;
    acc2 += hsh[rq * 4 + 2][k] * w;
    acc3 += hsh[rq * 4 + 3][k] * w;
  }
  const float bv = bfc[gc];
  const int r0 = by * 16 + rq * 4;
  logits[(size_t)(r0 + 0) * 1000 + gc] = acc0 + bv;
  logits[(size_t)(r0 + 1) * 1000 + gc] = acc1 + bv;
  logits[(size_t)(r0 + 2) * 1000 + gc] = acc2 + bv;
  logits[(size_t)(r0 + 3) * 1000 + gc] = acc3 + bv;
}

// ---------------------------------------------------------------- log_softmax over batch axis
__global__ __launch_bounds__(256) void lsm_kernel(const float* __restrict__ logits,
                                                  float* __restrict__ out)
{
  const int c = blockIdx.x, tid = threadIdx.x;
  const int wid = tid >> 6, lane = tid & 63;
  __shared__ float red[8];
  const float v = logits[(size_t)tid * 1000 + c];
  float m = v;
#pragma unroll
  for (int o = 32; o >= 1; o >>= 1) m = fmaxf(m, __shfl_xor(m, o));
  if (lane == 0) red[wid] = m;
  __syncthreads();
  m = fmaxf(fmaxf(red[0], red[1]), fmaxf(red[2], red[3]));
  float s = __expf(v - m);
#pragma unroll
  for (int o = 32; o >= 1; o >>= 1) s += __shfl_xor(s, o);
  if (lane == 0) red[4 + wid] = s;
  __syncthreads();
  s = red[4] + red[5] + red[6] + red[7];
  out[(size_t)tid * 1000 + c] = (v - m) - __logf(s);
}

// ---------------------------------------------------------------- launch
extern "C" void kernel_launch(void* const* d_in, const int* in_sizes, int n_in,
                              void* d_out, int out_size, void* d_ws, size_t ws_size,
                              hipStream_t stream) {
  (void)in_sizes; (void)n_in; (void)out_size;
  const float* x   = (const float*)d_in[0];
  const float* Wz  = (const float*)d_in[1];
  const float* bz  = (const float*)d_in[2];
  const float* Uz  = (const float*)d_in[3];
  const float* buz = (const float*)d_in[4];
  const float* Wr  = (const float*)d_in[5];
  const float* br  = (const float*)d_in[6];
  const float* Ur  = (const float*)d_in[7];
  const float* bur = (const float*)d_in[8];
  const float* Wh  = (const float*)d_in[9];
  const float* bh  = (const float*)d_in[10];
  const float* Uh  = (const float*)d_in[11];
  const float* buh = (const float*)d_in[12];
  const float* Wfc = (const float*)d_in[13];
  const float* bfc = (const float*)d_in[14];
  float* out = (float*)d_out;
  char* ws = (char*)d_ws;

  ushort_t* UT     = (ushort_t*)(ws + 0);        // 1572864 B
  ushort_t* WT     = (ushort_t*)(ws + 1572864);  // 1572864 B
  float*    gbias  = (float*)(ws + 3145728);     // 6144 B
  ushort_t* h_buf  = (ushort_t*)(ws + 3151872);  // 262144 B
  ushort_t* rh_buf = (ushort_t*)(ws + 3414016);  // 262144 B
  float*    hstate = (float*)(ws + 3676160);     // 524288 B
  float*    logits = (float*)(ws + 4200448);     // 1024000 B (256x1000)
  uint_t*   bars   = (uint_t*)(ws + 5224448);    // 2048 B
  ushort_t* gates  = (ushort_t*)(ws + 5226496);  // Tc*256*1536*2 B

  const size_t fixed = 5226496;
  const size_t per_step = (size_t)256 * 1536 * 2;
  int Tc_max = 2048;
  if (ws_size < fixed + (size_t)2048 * per_step) {
    const size_t avail = (ws_size > fixed) ? (ws_size - fixed) : 0;
    Tc_max = (int)(avail / per_step);
    Tc_max &= ~15;             // keep mtiles % 32 == 0 for the GEMM supertile swizzle
    if (Tc_max < 16) Tc_max = 16;
  }

  prep_kernel<<<3072, 256, 0, stream>>>(Wz, Wr, Wh, Uz, Ur, Uh,
                                        bz, buz, br, bur, bh, buh, UT, WT, gbias);

  int done = 0;
  while (done < 2048) {
    const int Tc = (2048 - done < Tc_max) ? (2048 - done) : Tc_max;
    const int mtiles = Tc * 2;  // Tc*256/128
    gate_gemm<<<mtiles * 12, 256, 0, stream>>>(x + (size_t)done * 256 * 512, WT, gbias, gates, mtiles);
    hipMemsetAsync(bars, 0, 2048, stream);
    gru_rec<<<256, 256, 0, stream>>>(UT, gates, h_buf, rh_buf, hstate, bars, Tc, done == 0 ? 1 : 0);
    done += Tc;
  }
  fc_kernel<<<dim3(16, 16), 256, 0, stream>>>(hstate, Wfc, bfc, logits);
  lsm_kernel<<<1000, 256, 0, stream>>>(logits, out);
}

// Round 2
// 10734.746 us; speedup vs baseline: 7.0315x; 7.0315x over previous
//
#include <hip/hip_runtime.h>

// CustomRNN (GRU, SEQ=2048, B=256, D=512) + FC(1000) + log_softmax over batch axis.
//
//   prep_kernel : cast U->UT bf16 [3][512 n][512 k], W->WT bf16 [1536 n][512 k], fold biases
//   gate_gemm   : gates[t,b,1536] = x[t,b,:] @ [Wz|Wr|Wh] + (b+bu)   (bf16 MFMA)
//   gru_rec     : persistent kernel, 256 blocks = 16 groups x 16 col-slice blocks.
//                 Group g = blocks {bid : bid&15==g} -> all on XCD g%8 (round-robin dispatch).
//                 Sync is XCD-LOCAL: TCC atomics (global_atomic_add sc0, no sc1/threadfence),
//                 data exchange through the shared per-XCD L2 (sc0 loads bypass stale L1).
//   fc_kernel   : logits = relu(h_final) @ Wfc + bfc
//   lsm_kernel  : log_softmax over the 256-batch axis per class column.

typedef unsigned short ushort_t;
typedef unsigned int uint_t;
typedef __bf16 bf16_t;
typedef bf16_t bf16x8 __attribute__((ext_vector_type(8)));
typedef float f32x4 __attribute__((ext_vector_type(4)));
typedef uint_t u32x4 __attribute__((ext_vector_type(4)));

__device__ __forceinline__ ushort_t f2bf(float f) {
  uint_t u = __float_as_uint(f);
  u += 0x7FFFu + ((u >> 16) & 1u);   // round-to-nearest-even
  return (ushort_t)(u >> 16);
}
__device__ __forceinline__ float bf2f(ushort_t h) {
  return __uint_as_float(((uint_t)h) << 16);
}

// TCC-local atomic add with return (executes at this XCD's L2; no sc1 -> never goes to MALL).
__device__ __forceinline__ uint_t atom_add_ret(uint_t* p, uint_t v) {
  uint_t old;
  asm volatile("global_atomic_add %0, %1, %2, off sc0\n\t"
               "s_waitcnt vmcnt(0)"
               : "=v"(old) : "v"(p), "v"(v) : "memory");
  return old;
}

// ---------------------------------------------------------------- prep
__global__ __launch_bounds__(256) void prep_kernel(
    const float* __restrict__ Wz, const float* __restrict__ Wr, const float* __restrict__ Wh,
    const float* __restrict__ Uz, const float* __restrict__ Ur, const float* __restrict__ Uh,
    const float* __restrict__ bz, const float* __restrict__ buz,
    const float* __restrict__ br, const float* __restrict__ bur,
    const float* __restrict__ bh, const float* __restrict__ buh,
    ushort_t* __restrict__ UT, ushort_t* __restrict__ WT, float* __restrict__ gbias)
{
  const int idx = blockIdx.x * 256 + threadIdx.x;  // exactly 786432 threads
  {
    const int gate = idx >> 18, n = (idx >> 9) & 511, k = idx & 511;
    const float* U = (gate == 0) ? Uz : (gate == 1 ? Ur : Uh);
    UT[idx] = f2bf(U[k * 512 + n]);                 // UT[gate][n][k] = U[k][n]
  }
  {
    const int n = idx >> 9, k = idx & 511;
    const int gate = n >> 9, nn = n & 511;
    const float* W = (gate == 0) ? Wz : (gate == 1 ? Wr : Wh);
    WT[idx] = f2bf(W[k * 512 + nn]);                // WT[n][k] = W[k][n]
  }
  if (idx < 1536) {
    const int gate = idx >> 9, nn = idx & 511;
    gbias[idx] = (gate == 0) ? (bz[nn] + buz[nn])
               : (gate == 1) ? (br[nn] + bur[nn])
                             : (bh[nn] + buh[nn]);
  }
}

// ---------------------------------------------------------------- gate GEMM
__global__ __launch_bounds__(256) void gate_gemm(
    const float* __restrict__ x,
    const ushort_t* __restrict__ WT,     // [1536][512] (n-major)
    const float* __restrict__ gbias,
    ushort_t* __restrict__ gout,         // [M][1536]
    int mtiles)
{
  __shared__ ushort_t A_sh[128 * 72];
  __shared__ ushort_t B_sh[128 * 72];
  const int bid = blockIdx.x;
  int mt, nt;
  if ((mtiles & 31) == 0) {              // supertile 32 mtiles x 12 ntiles for A L2/L3 reuse
    const int sb = bid / 384;
    const int r = bid - sb * 384;
    mt = sb * 32 + (r & 31);
    nt = r >> 5;
  } else {
    mt = bid / 12;
    nt = bid - mt * 12;
  }
  const int mrow0 = mt * 128;
  const int ncol0 = nt * 128;
  const int tid = threadIdx.x;
  const int wid = tid >> 6;
  const int lane = tid & 63;
  const int wm = wid >> 1, wn = wid & 1;
  const int l15 = lane & 15, l4 = lane >> 4;

  const f32x4 vzero = {0.f, 0.f, 0.f, 0.f};
  f32x4 acc[4][4];
#pragma unroll
  for (int m = 0; m < 4; ++m) {
#pragma unroll
    for (int n = 0; n < 4; ++n) acc[m][n] = vzero;
  }

  const int ar = tid >> 4;
  const int ak = tid & 15;
  const int bn = tid >> 3;
  const int bk = tid & 7;

  for (int ks = 0; ks < 8; ++ks) {
    if (ks) __syncthreads();
    const int k0 = ks * 64;
#pragma unroll
    for (int p = 0; p < 8; ++p) {
      const int r = p * 16 + ar;
      const float4 v = *(const float4*)&x[(size_t)(mrow0 + r) * 512 + (k0 + ak * 4)];
      ushort4 hv;
      hv.x = f2bf(v.x); hv.y = f2bf(v.y); hv.z = f2bf(v.z); hv.w = f2bf(v.w);
      *(ushort4*)&A_sh[r * 72 + ak * 4] = hv;
    }
#pragma unroll
    for (int p = 0; p < 4; ++p) {
      const int n = p * 32 + bn;
      *(uint4*)&B_sh[n * 72 + bk * 8] =
          *(const uint4*)&WT[(size_t)(ncol0 + n) * 512 + (k0 + bk * 8)];
    }
    __syncthreads();
#pragma unroll
    for (int kk = 0; kk < 2; ++kk) {
      bf16x8 a[4], b[4];
#pragma unroll
      for (int m = 0; m < 4; ++m)
        a[m] = *(const bf16x8*)&A_sh[(wm * 64 + m * 16 + l15) * 72 + kk * 32 + l4 * 8];
#pragma unroll
      for (int n = 0; n < 4; ++n)
        b[n] = *(const bf16x8*)&B_sh[(wn * 64 + n * 16 + l15) * 72 + kk * 32 + l4 * 8];
#pragma unroll
      for (int m = 0; m < 4; ++m) {
#pragma unroll
        for (int n = 0; n < 4; ++n)
          acc[m][n] = __builtin_amdgcn_mfma_f32_16x16x32_bf16(a[m], b[n], acc[m][n], 0, 0, 0);
      }
    }
  }
#pragma unroll
  for (int n = 0; n < 4; ++n) {
    const int gcol = ncol0 + wn * 64 + n * 16 + l15;
    const float bv = gbias[gcol];
#pragma unroll
    for (int m = 0; m < 4; ++m) {
      const int grow = mrow0 + wm * 64 + m * 16 + l4 * 4;
#pragma unroll
      for (int q = 0; q < 4; ++q)
        gout[(size_t)(grow + q) * 1536 + gcol] = f2bf(acc[m][n][q] + bv);
    }
  }
}

// ---------------------------------------------------------------- XCD-local group barrier
// Monotone counter per group; arrival = add 1, wait = poll until ctr >= 16*n.
// All participants are on the same XCD, so the TCC RMWs are coherent and fast.
__device__ __forceinline__ bool group_barrier(uint_t* ctr, uint_t target, int tid, int* s_dead) {
  asm volatile("s_waitcnt vmcnt(0)" ::: "memory");  // own stores committed to L2
  __syncthreads();                                   // all waves drained
  if (tid == 0) {
    uint_t seen = atom_add_ret(ctr, 1u) + 1u;
    int cnt = 0;
    while (seen < target) {
      __builtin_amdgcn_s_sleep(1);
      seen = atom_add_ret(ctr, 0u);                  // RMW -> always served at TCC
      if (++cnt > (1 << 15)) { *s_dead = 1; break; } // co-location broken: fast-fail
    }
  }
  __syncthreads();
  return *s_dead != 0;
}

// Stage a [16 rows][512] bf16 tile (16 KB) from global (shared L2) into LDS.
// sc0 loads bypass the (possibly stale) L1; one batched asm, single waitcnt.
__device__ __forceinline__ void stage16x512(const ushort_t* __restrict__ src, int g,
                                            ushort_t* dst_lds, int tid) {
  const ushort_t* p[4];
#pragma unroll
  for (int k = 0; k < 4; ++k) {
    const int idx = tid + (k << 8);
    const int r = idx >> 6, kc = idx & 63;
    p[k] = src + (((g * 16 + r) << 9) + kc * 8);
  }
  u32x4 v0, v1, v2, v3;
  asm volatile(
      "global_load_dwordx4 %0, %4, off sc0\n\t"
      "global_load_dwordx4 %1, %5, off sc0\n\t"
      "global_load_dwordx4 %2, %6, off sc0\n\t"
      "global_load_dwordx4 %3, %7, off sc0\n\t"
      "s_waitcnt vmcnt(0)"
      : "=&v"(v0), "=&v"(v1), "=&v"(v2), "=&v"(v3)
      : "v"(p[0]), "v"(p[1]), "v"(p[2]), "v"(p[3])
      : "memory");
#pragma unroll
  for (int k = 0; k < 4; ++k) {
    const int idx = tid + (k << 8);
    const int r = idx >> 6, kc = idx & 63;
    *(u32x4*)&dst_lds[r * 520 + kc * 8] = (k == 0) ? v0 : (k == 1) ? v1 : (k == 2) ? v2 : v3;
  }
}

// ---------------------------------------------------------------- persistent GRU recurrence
__global__ __launch_bounds__(256, 1) void gru_rec(
    const ushort_t* __restrict__ UT,     // [3][512 n][512 k] bf16
    const ushort_t* __restrict__ gates,  // [Tc][256][1536] bf16
    ushort_t* __restrict__ h_buf,        // [256][512] bf16
    ushort_t* __restrict__ rh_buf,       // [256][512] bf16
    float* __restrict__ h_state,         // [256][512] fp32
    uint_t* __restrict__ bars,
    int Tc, int first)
{
  __shared__ ushort_t h_st[16 * 520];
  __shared__ float z_sh[512];
  __shared__ float hown[512];
  __shared__ float red[512];
  __shared__ int s_dead;

  const int tid = threadIdx.x;
  const int bid = blockIdx.x;
  const int g = bid & 15;
  const int j = bid >> 4;
  const int wid = tid >> 6;
  const int lane = tid & 63;
  const int l15 = lane & 15;
  const int l4 = lane >> 4;
  if (tid == 0) s_dead = 0;

  uint_t* ctr = bars + g * 64;          // one counter per group, own cacheline
  uint_t nbar = 0;

  const int p1gate = wid >> 1;  // phase1: waves 0,1 -> z ; waves 2,3 -> r
  const int p1nt = wid & 1;
  const int p2nt = wid >> 1;    // phase2 subtile
  const int p2kh = wid & 1;     // phase2 K half

  // U fragments persistent in registers
  bf16x8 UB[16];
  {
    const size_t base = (size_t)((p1gate << 9) + j * 32 + p1nt * 16 + l15) * 512 + (size_t)(l4 * 8);
#pragma unroll
    for (int kk = 0; kk < 16; ++kk) UB[kk] = *(const bf16x8*)&UT[base + (size_t)kk * 32];
  }
  bf16x8 UH[8];
  {
    const size_t base = (size_t)(1024 + j * 32 + p2nt * 16 + l15) * 512 + (size_t)(p2kh * 256 + l4 * 8);
#pragma unroll
    for (int kk = 0; kk < 8; ++kk) UH[kk] = *(const bf16x8*)&UT[base + (size_t)kk * 32];
  }

  if (first) {
    for (int i = tid; i < 512; i += 256) {
      const int r = i >> 5, c = i & 31;
      h_buf[((g * 16 + r) << 9) + j * 32 + c] = 0;
      hown[i] = 0.f;
    }
  } else {
    for (int i = tid; i < 512; i += 256) {
      const int r = i >> 5, c = i & 31;
      hown[i] = h_state[((g * 16 + r) << 9) + j * 32 + c];
    }
  }
  if (group_barrier(ctr, (++nbar) * 16, tid, &s_dead)) return;

  const int colg1 = j * 32 + p1nt * 16 + l15;
  const int colg2 = j * 32 + p2nt * 16 + l15;

  // software-pipelined gate loads: cur for step tt, nxt issued before barrier2
  float c1[4], c2[4], n1[4], n2[4];
  {
    const size_t gb = (size_t)(g * 16) * 1536;
#pragma unroll
    for (int q = 0; q < 4; ++q) {
      c1[q] = bf2f(gates[gb + (size_t)(l4 * 4 + q) * 1536 + (p1gate << 9) + colg1]);
      c2[q] = bf2f(gates[gb + (size_t)(l4 * 4 + q) * 1536 + 1024 + colg2]);
    }
  }

  for (int tt = 0; tt < Tc; ++tt) {
    // ---- phase 1: z, r from h
    stage16x512(h_buf, g, h_st, tid);
    __syncthreads();
    {
      const ushort_t* ap = &h_st[l15 * 520 + l4 * 8];
      f32x4 a0 = {0.f, 0.f, 0.f, 0.f}, a1 = {0.f, 0.f, 0.f, 0.f};
#pragma unroll
      for (int kk = 0; kk < 16; kk += 2) {
        a0 = __builtin_amdgcn_mfma_f32_16x16x32_bf16(*(const bf16x8*)(ap + kk * 32), UB[kk], a0, 0, 0, 0);
        a1 = __builtin_amdgcn_mfma_f32_16x16x32_bf16(*(const bf16x8*)(ap + kk * 32 + 32), UB[kk + 1], a1, 0, 0, 0);
      }
      const f32x4 acc = a0 + a1;
      const int lc = p1nt * 16 + l15;
#pragma unroll
      for (int q = 0; q < 4; ++q) {
        const int row = l4 * 4 + q;
        const float pre = acc[q] + c1[q];
        const float s = 1.f / (1.f + __expf(-pre));
        if (p1gate == 0) z_sh[row * 32 + lc] = s;
        else rh_buf[((g * 16 + row) << 9) + j * 32 + lc] = f2bf(s * hown[row * 32 + lc]);
      }
    }
    if (group_barrier(ctr, (++nbar) * 16, tid, &s_dead)) break;

    // ---- phase 2: h~ from (r*h), h update
    stage16x512(rh_buf, g, h_st, tid);
    __syncthreads();
    {
      const ushort_t* ap = &h_st[l15 * 520 + p2kh * 256 + l4 * 8];
      f32x4 a0 = {0.f, 0.f, 0.f, 0.f}, a1 = {0.f, 0.f, 0.f, 0.f};
#pragma unroll
      for (int kk = 0; kk < 8; kk += 2) {
        a0 = __builtin_amdgcn_mfma_f32_16x16x32_bf16(*(const bf16x8*)(ap + kk * 32), UH[kk], a0, 0, 0, 0);
        a1 = __builtin_amdgcn_mfma_f32_16x16x32_bf16(*(const bf16x8*)(ap + kk * 32 + 32), UH[kk + 1], a1, 0, 0, 0);
      }
      const f32x4 acc = a0 + a1;
      if (p2kh == 1) {
#pragma unroll
        for (int q = 0; q < 4; ++q) red[p2nt * 256 + (l4 * 4 + q) * 16 + l15] = acc[q];
      }
      // issue next-step gate loads; HBM latency hides under epilogue + barrier poll
      if (tt + 1 < Tc) {
        const size_t gb = (size_t)((size_t)(tt + 1) * 256 + g * 16) * 1536;
#pragma unroll
        for (int q = 0; q < 4; ++q) {
          n1[q] = bf2f(gates[gb + (size_t)(l4 * 4 + q) * 1536 + (p1gate << 9) + colg1]);
          n2[q] = bf2f(gates[gb + (size_t)(l4 * 4 + q) * 1536 + 1024 + colg2]);
        }
      }
      __syncthreads();
      if (p2kh == 0) {
        const int lc = p2nt * 16 + l15;
#pragma unroll
        for (int q = 0; q < 4; ++q) {
          const int row = l4 * 4 + q;
          const float dot = acc[q] + red[p2nt * 256 + row * 16 + l15];
          float pre = dot + c2[q];
          pre = fminf(15.f, fmaxf(-15.f, pre));
          const float e = __expf(2.f * pre);
          const float th = (e - 1.f) / (e + 1.f);
          const float z = z_sh[row * 32 + lc];
          const float hold = hown[row * 32 + lc];
          const float hnew = (1.f - z) * hold + z * th;
          hown[row * 32 + lc] = hnew;
          h_buf[((g * 16 + row) << 9) + j * 32 + lc] = f2bf(hnew);
          if (tt == Tc - 1) h_state[((g * 16 + row) << 9) + j * 32 + lc] = hnew;
        }
      }
    }
    if (group_barrier(ctr, (++nbar) * 16, tid, &s_dead)) break;
#pragma unroll
    for (int q = 0; q < 4; ++q) { c1[q] = n1[q]; c2[q] = n2[q]; }
  }
}

// ---------------------------------------------------------------- FC: logits = relu(h) @ Wfc + bfc
__global__ __launch_bounds__(256) void fc_kernel(
    const float* __restrict__ h, const float* __restrict__ Wfc,
    const float* __restrict__ bfc, float* __restrict__ logits)
{
  __shared__ float hsh[16][520];
  const int tid = threadIdx.x;
  const int by = blockIdx.y;
  {
    const int r = tid >> 4, seg = tid & 15;
    const float* src = &h[(size_t)(by * 16 + r) * 512 + seg * 32];
#pragma unroll
    for (int i = 0; i < 8; ++i) {
      float4 v = *(const float4*)&src[i * 4];
      v.x = fmaxf(v.x, 0.f); v.y = fmaxf(v.y, 0.f);
      v.z = fmaxf(v.z, 0.f); v.w = fmaxf(v.w, 0.f);
      *(float4*)&hsh[r][seg * 32 + i * 4] = v;
    }
  }
  __syncthreads();
  const int c = tid & 63, rq = tid >> 6;
  const int gc = blockIdx.x * 64 + c;
  if (gc >= 1000) return;
  float acc0 = 0.f, acc1 = 0.f, acc2 = 0.f, acc3 = 0.f;
  for (int k = 0; k < 512; ++k) {
    const float w = Wfc[(size_t)k * 1000 + gc];
    acc0 += hsh[rq * 4 + 0][k] * w;
    acc1 += hsh[rq * 4 + 1][k] * w;
    acc2 += hsh[rq * 4 + 2][k] * w;
    acc3 += hsh[rq * 4 + 3][k] * w;
  }
  const float bv = bfc[gc];
  const int r0 = by * 16 + rq * 4;
  logits[(size_t)(r0 + 0) * 1000 + gc] = acc0 + bv;
  logits[(size_t)(r0 + 1) * 1000 + gc] = acc1 + bv;
  logits[(size_t)(r0 + 2) * 1000 + gc] = acc2 + bv;
  logits[(size_t)(r0 + 3) * 1000 + gc] = acc3 + bv;
}

// ---------------------------------------------------------------- log_softmax over batch axis
__global__ __launch_bounds__(256) void lsm_kernel(const float* __restrict__ logits,
                                                  float* __restrict__ out)
{
  const int c = blockIdx.x, tid = threadIdx.x;
  const int wid = tid >> 6, lane = tid & 63;
  __shared__ float red[8];
  const float v = logits[(size_t)tid * 1000 + c];
  float m = v;
#pragma unroll
  for (int o = 32; o >= 1; o >>= 1) m = fmaxf(m, __shfl_xor(m, o));
  if (lane == 0) red[wid] = m;
  __syncthreads();
  m = fmaxf(fmaxf(red[0], red[1]), fmaxf(red[2], red[3]));
  float s = __expf(v - m);
#pragma unroll
  for (int o = 32; o >= 1; o >>= 1) s += __shfl_xor(s, o);
  if (lane == 0) red[4 + wid] = s;
  __syncthreads();
  s = red[4] + red[5] + red[6] + red[7];
  out[(size_t)tid * 1000 + c] = (v - m) - __logf(s);
}

// ---------------------------------------------------------------- launch
extern "C" void kernel_launch(void* const* d_in, const int* in_sizes, int n_in,
                              void* d_out, int out_size, void* d_ws, size_t ws_size,
                              hipStream_t stream) {
  (void)in_sizes; (void)n_in; (void)out_size;
  const float* x   = (const float*)d_in[0];
  const float* Wz  = (const float*)d_in[1];
  const float* bz  = (const float*)d_in[2];
  const float* Uz  = (const float*)d_in[3];
  const float* buz = (const float*)d_in[4];
  const float* Wr  = (const float*)d_in[5];
  const float* br  = (const float*)d_in[6];
  const float* Ur  = (const float*)d_in[7];
  const float* bur = (const float*)d_in[8];
  const float* Wh  = (const float*)d_in[9];
  const float* bh  = (const float*)d_in[10];
  const float* Uh  = (const float*)d_in[11];
  const float* buh = (const float*)d_in[12];
  const float* Wfc = (const float*)d_in[13];
  const float* bfc = (const float*)d_in[14];
  float* out = (float*)d_out;
  char* ws = (char*)d_ws;

  ushort_t* UT     = (ushort_t*)(ws + 0);        // 1572864 B
  ushort_t* WT     = (ushort_t*)(ws + 1572864);  // 1572864 B
  float*    gbias  = (float*)(ws + 3145728);     // 6144 B
  ushort_t* h_buf  = (ushort_t*)(ws + 3151872);  // 262144 B
  ushort_t* rh_buf = (ushort_t*)(ws + 3414016);  // 262144 B
  float*    hstate = (float*)(ws + 3676160);     // 524288 B
  float*    logits = (float*)(ws + 4200448);     // 1024000 B (256x1000)
  uint_t*   bars   = (uint_t*)(ws + 5224448);    // 4096 B (16 groups x 256B)
  ushort_t* gates  = (ushort_t*)(ws + 5228544);  // Tc*256*1536*2 B

  const size_t fixed = 5228544;
  const size_t per_step = (size_t)256 * 1536 * 2;
  int Tc_max = 2048;
  if (ws_size < fixed + (size_t)2048 * per_step) {
    const size_t avail = (ws_size > fixed) ? (ws_size - fixed) : 0;
    Tc_max = (int)(avail / per_step);
    Tc_max &= ~15;             // keep mtiles % 32 == 0 for the GEMM supertile swizzle
    if (Tc_max < 16) Tc_max = 16;
  }

  prep_kernel<<<3072, 256, 0, stream>>>(Wz, Wr, Wh, Uz, Ur, Uh,
                                        bz, buz, br, bur, bh, buh, UT, WT, gbias);

  int done = 0;
  while (done < 2048) {
    const int Tc = (2048 - done < Tc_max) ? (2048 - done) : Tc_max;
    const int mtiles = Tc * 2;  // Tc*256/128
    gate_gemm<<<mtiles * 12, 256, 0, stream>>>(x + (size_t)done * 256 * 512, WT, gbias, gates, mtiles);
    hipMemsetAsync(bars, 0, 4096, stream);
    gru_rec<<<256, 256, 0, stream>>>(UT, gates, h_buf, rh_buf, hstate, bars, Tc, done == 0 ? 1 : 0);
    done += Tc;
  }
  fc_kernel<<<dim3(16, 16), 256, 0, stream>>>(hstate, Wfc, bfc, logits);
  lsm_kernel<<<1000, 256, 0, stream>>>(logits, out);
}

// Round 3
// 9956.891 us; speedup vs baseline: 7.5809x; 1.0781x over previous
//
#include <hip/hip_runtime.h>

// CustomRNN (GRU, SEQ=2048, B=256, D=512) + FC(1000) + log_softmax over batch axis.
//
//   prep_kernel : cast U->UT bf16 [3][512 n][512 k], W->WT bf16 [1536 n][512 k], fold biases
//   gate_gemm   : gates[t,b,1536] = x[t,b,:] @ [Wz|Wr|Wh] + (b+bu)   (bf16 MFMA)
//   gru_rec     : persistent kernel, 256 blocks = 16 groups x 16 col-slice blocks.
//                 Group g = blocks {bid : bid&15==g} -> all on XCD g%8 (round-robin dispatch).
//                 Sync is XCD-LOCAL: TCC atomics (sc0, no sc1/threadfence), h/rh through the
//                 shared per-XCD L2. Gate loads for step t+1 issued as raw asm loads AFTER the
//                 store-drain of step t's last barrier -> they fly across the barrier poll and
//                 are guaranteed complete by the next stage's vmcnt(0).
//   fc_kernel   : logits = relu(h_final) @ Wfc + bfc
//   lsm_kernel  : log_softmax over the 256-batch axis per class column.

typedef unsigned short ushort_t;
typedef unsigned int uint_t;
typedef __bf16 bf16_t;
typedef bf16_t bf16x8 __attribute__((ext_vector_type(8)));
typedef float f32x4 __attribute__((ext_vector_type(4)));
typedef uint_t u32x4 __attribute__((ext_vector_type(4)));

__device__ __forceinline__ ushort_t f2bf(float f) {
  uint_t u = __float_as_uint(f);
  u += 0x7FFFu + ((u >> 16) & 1u);   // round-to-nearest-even
  return (ushort_t)(u >> 16);
}
__device__ __forceinline__ float bfu2f(uint_t h) {
  return __uint_as_float(h << 16);
}

// TCC-local atomic add WITH return (waits). Used only for polling.
__device__ __forceinline__ uint_t atom_add_ret(uint_t* p, uint_t v) {
  uint_t old;
  asm volatile("global_atomic_add %0, %1, %2, off sc0\n\t"
               "s_waitcnt vmcnt(0)"
               : "=v"(old) : "v"(p), "v"(v) : "memory");
  return old;
}
// Fire-and-forget atomic add (no return -> no wait).
__device__ __forceinline__ void atom_add_noret(uint_t* p, uint_t v) {
  asm volatile("global_atomic_add %0, %1, off" :: "v"(p), "v"(v) : "memory");
}

// Raw u16 load: issues immediately, NO compiler-tracked wait. Value is only
// safe to read after a subsequent s_waitcnt vmcnt(0) (stage16x512 provides it).
#define GLOAD_U16(dst, ptr, off) \
  asm volatile("global_load_ushort %0, %1, off offset:" #off : "=v"(dst) : "v"(ptr))

// ---------------------------------------------------------------- prep
__global__ __launch_bounds__(256) void prep_kernel(
    const float* __restrict__ Wz, const float* __restrict__ Wr, const float* __restrict__ Wh,
    const float* __restrict__ Uz, const float* __restrict__ Ur, const float* __restrict__ Uh,
    const float* __restrict__ bz, const float* __restrict__ buz,
    const float* __restrict__ br, const float* __restrict__ bur,
    const float* __restrict__ bh, const float* __restrict__ buh,
    ushort_t* __restrict__ UT, ushort_t* __restrict__ WT, float* __restrict__ gbias)
{
  const int idx = blockIdx.x * 256 + threadIdx.x;  // exactly 786432 threads
  {
    const int gate = idx >> 18, n = (idx >> 9) & 511, k = idx & 511;
    const float* U = (gate == 0) ? Uz : (gate == 1 ? Ur : Uh);
    UT[idx] = f2bf(U[k * 512 + n]);                 // UT[gate][n][k] = U[k][n]
  }
  {
    const int n = idx >> 9, k = idx & 511;
    const int gate = n >> 9, nn = n & 511;
    const float* W = (gate == 0) ? Wz : (gate == 1 ? Wr : Wh);
    WT[idx] = f2bf(W[k * 512 + nn]);                // WT[n][k] = W[k][n]
  }
  if (idx < 1536) {
    const int gate = idx >> 9, nn = idx & 511;
    gbias[idx] = (gate == 0) ? (bz[nn] + buz[nn])
               : (gate == 1) ? (br[nn] + bur[nn])
                             : (bh[nn] + buh[nn]);
  }
}

// ---------------------------------------------------------------- gate GEMM
__global__ __launch_bounds__(256) void gate_gemm(
    const float* __restrict__ x,
    const ushort_t* __restrict__ WT,     // [1536][512] (n-major)
    const float* __restrict__ gbias,
    ushort_t* __restrict__ gout,         // [M][1536]
    int mtiles)
{
  __shared__ ushort_t A_sh[128 * 72];
  __shared__ ushort_t B_sh[128 * 72];
  const int bid = blockIdx.x;
  int mt, nt;
  if ((mtiles & 31) == 0) {              // supertile 32 mtiles x 12 ntiles for A L2/L3 reuse
    const int sb = bid / 384;
    const int r = bid - sb * 384;
    mt = sb * 32 + (r & 31);
    nt = r >> 5;
  } else {
    mt = bid / 12;
    nt = bid - mt * 12;
  }
  const int mrow0 = mt * 128;
  const int ncol0 = nt * 128;
  const int tid = threadIdx.x;
  const int wid = tid >> 6;
  const int lane = tid & 63;
  const int wm = wid >> 1, wn = wid & 1;
  const int l15 = lane & 15, l4 = lane >> 4;

  const f32x4 vzero = {0.f, 0.f, 0.f, 0.f};
  f32x4 acc[4][4];
#pragma unroll
  for (int m = 0; m < 4; ++m) {
#pragma unroll
    for (int n = 0; n < 4; ++n) acc[m][n] = vzero;
  }

  const int ar = tid >> 4;
  const int ak = tid & 15;
  const int bn = tid >> 3;
  const int bk = tid & 7;

  for (int ks = 0; ks < 8; ++ks) {
    if (ks) __syncthreads();
    const int k0 = ks * 64;
#pragma unroll
    for (int p = 0; p < 8; ++p) {
      const int r = p * 16 + ar;
      const float4 v = *(const float4*)&x[(size_t)(mrow0 + r) * 512 + (k0 + ak * 4)];
      ushort4 hv;
      hv.x = f2bf(v.x); hv.y = f2bf(v.y); hv.z = f2bf(v.z); hv.w = f2bf(v.w);
      *(ushort4*)&A_sh[r * 72 + ak * 4] = hv;
    }
#pragma unroll
    for (int p = 0; p < 4; ++p) {
      const int n = p * 32 + bn;
      *(uint4*)&B_sh[n * 72 + bk * 8] =
          *(const uint4*)&WT[(size_t)(ncol0 + n) * 512 + (k0 + bk * 8)];
    }
    __syncthreads();
#pragma unroll
    for (int kk = 0; kk < 2; ++kk) {
      bf16x8 a[4], b[4];
#pragma unroll
      for (int m = 0; m < 4; ++m)
        a[m] = *(const bf16x8*)&A_sh[(wm * 64 + m * 16 + l15) * 72 + kk * 32 + l4 * 8];
#pragma unroll
      for (int n = 0; n < 4; ++n)
        b[n] = *(const bf16x8*)&B_sh[(wn * 64 + n * 16 + l15) * 72 + kk * 32 + l4 * 8];
#pragma unroll
      for (int m = 0; m < 4; ++m) {
#pragma unroll
        for (int n = 0; n < 4; ++n)
          acc[m][n] = __builtin_amdgcn_mfma_f32_16x16x32_bf16(a[m], b[n], acc[m][n], 0, 0, 0);
      }
    }
  }
#pragma unroll
  for (int n = 0; n < 4; ++n) {
    const int gcol = ncol0 + wn * 64 + n * 16 + l15;
    const float bv = gbias[gcol];
#pragma unroll
    for (int m = 0; m < 4; ++m) {
      const int grow = mrow0 + wm * 64 + m * 16 + l4 * 4;
#pragma unroll
      for (int q = 0; q < 4; ++q)
        gout[(size_t)(grow + q) * 1536 + gcol] = f2bf(acc[m][n][q] + bv);
    }
  }
}

// ---------------------------------------------------------------- XCD-local group barrier
// Monotone counter; arrival = non-blocking add, wait = poll RMW until ctr >= 16*n.
__device__ __forceinline__ bool group_barrier(uint_t* ctr, uint_t target, int tid, int* s_dead) {
  asm volatile("s_waitcnt vmcnt(0)" ::: "memory");  // own stores committed to L2
  __syncthreads();                                   // all waves drained
  if (tid == 0) {
    atom_add_noret(ctr, 1u);
    int cnt = 0;
    for (;;) {
      const uint_t seen = atom_add_ret(ctr, 0u);     // RMW -> always served at TCC
      if (seen >= target) break;
      __builtin_amdgcn_s_sleep(1);
      if (++cnt > (1 << 15)) { *s_dead = 1; break; } // co-location broken: fast-fail
    }
  }
  __syncthreads();
  return *s_dead != 0;
}

// Stage a [16 rows][512] bf16 tile (16 KB) from global (shared L2) into LDS.
// sc0 loads bypass the (possibly stale) L1; ends with vmcnt(0) -> also the
// safety point for any raw GLOAD_U16 issued earlier.
__device__ __forceinline__ void stage16x512(const ushort_t* __restrict__ src, int g,
                                            ushort_t* dst_lds, int tid) {
  const ushort_t* p[4];
#pragma unroll
  for (int k = 0; k < 4; ++k) {
    const int idx = tid + (k << 8);
    const int r = idx >> 6, kc = idx & 63;
    p[k] = src + (((g * 16 + r) << 9) + kc * 8);
  }
  u32x4 v0, v1, v2, v3;
  asm volatile(
      "global_load_dwordx4 %0, %4, off sc0\n\t"
      "global_load_dwordx4 %1, %5, off sc0\n\t"
      "global_load_dwordx4 %2, %6, off sc0\n\t"
      "global_load_dwordx4 %3, %7, off sc0\n\t"
      "s_waitcnt vmcnt(0)"
      : "=&v"(v0), "=&v"(v1), "=&v"(v2), "=&v"(v3)
      : "v"(p[0]), "v"(p[1]), "v"(p[2]), "v"(p[3])
      : "memory");
#pragma unroll
  for (int k = 0; k < 4; ++k) {
    const int idx = tid + (k << 8);
    const int r = idx >> 6, kc = idx & 63;
    *(u32x4*)&dst_lds[r * 520 + kc * 8] = (k == 0) ? v0 : (k == 1) ? v1 : (k == 2) ? v2 : v3;
  }
}

// ---------------------------------------------------------------- persistent GRU recurrence
__global__ __launch_bounds__(256, 1) void gru_rec(
    const ushort_t* __restrict__ UT,     // [3][512 n][512 k] bf16
    const ushort_t* __restrict__ gates,  // [Tc][256][1536] bf16
    ushort_t* __restrict__ h_buf,        // [256][512] bf16
    ushort_t* __restrict__ rh_buf,       // [256][512] bf16
    float* __restrict__ h_state,         // [256][512] fp32
    uint_t* __restrict__ bars,
    int Tc, int first)
{
  __shared__ ushort_t h_st[16 * 520];
  __shared__ float z_sh[512];
  __shared__ float hown[512];
  __shared__ float red[512];
  __shared__ int s_dead;

  const int tid = threadIdx.x;
  const int bid = blockIdx.x;
  const int g = bid & 15;
  const int j = bid >> 4;
  const int wid = tid >> 6;
  const int lane = tid & 63;
  const int l15 = lane & 15;
  const int l4 = lane >> 4;
  if (tid == 0) s_dead = 0;

  uint_t* ctr = bars + g * 64;          // one counter per group, own cacheline
  uint_t nbar = 0;

  const int p1gate = wid >> 1;  // phase1: waves 0,1 -> z ; waves 2,3 -> r
  const int p1nt = wid & 1;
  const int p2nt = wid >> 1;    // phase2 subtile
  const int p2kh = wid & 1;     // phase2 K half

  // U fragments persistent in registers
  bf16x8 UB[16];
  {
    const size_t base = (size_t)((p1gate << 9) + j * 32 + p1nt * 16 + l15) * 512 + (size_t)(l4 * 8);
#pragma unroll
    for (int kk = 0; kk < 16; ++kk) UB[kk] = *(const bf16x8*)&UT[base + (size_t)kk * 32];
  }
  bf16x8 UH[8];
  {
    const size_t base = (size_t)(1024 + j * 32 + p2nt * 16 + l15) * 512 + (size_t)(p2kh * 256 + l4 * 8);
#pragma unroll
    for (int kk = 0; kk < 8; ++kk) UH[kk] = *(const bf16x8*)&UT[base + (size_t)kk * 32];
  }

  if (first) {
    for (int i = tid; i < 512; i += 256) {
      const int r = i >> 5, c = i & 31;
      h_buf[((g * 16 + r) << 9) + j * 32 + c] = 0;
      hown[i] = 0.f;
    }
  } else {
    for (int i = tid; i < 512; i += 256) {
      const int r = i >> 5, c = i & 31;
      hown[i] = h_state[((g * 16 + r) << 9) + j * 32 + c];
    }
  }
  if (group_barrier(ctr, (++nbar) * 16, tid, &s_dead)) return;

  const int colg1 = j * 32 + p1nt * 16 + l15;
  const int colg2 = j * 32 + p2nt * 16 + l15;

  // gate pipeline registers: n* loaded (possibly via raw asm) for step tt,
  // copied to c* only after a vmcnt(0) drain (stage16x512) -> hardware-safe.
  uint_t c1u[4], c2u[4], n1u[4], n2u[4];
  {
    const size_t gb = (size_t)(g * 16) * 1536;
#pragma unroll
    for (int q = 0; q < 4; ++q) {
      n1u[q] = gates[gb + (size_t)(l4 * 4 + q) * 1536 + (p1gate << 9) + colg1];
      n2u[q] = gates[gb + (size_t)(l4 * 4 + q) * 1536 + 1024 + colg2];
    }
  }

  for (int tt = 0; tt < Tc; ++tt) {
    // ---- phase 1: z, r from h
    stage16x512(h_buf, g, h_st, tid);      // ends vmcnt(0): n1u/n2u now valid
    __syncthreads();
#pragma unroll
    for (int q = 0; q < 4; ++q) { c1u[q] = n1u[q]; c2u[q] = n2u[q]; }
    {
      const ushort_t* ap = &h_st[l15 * 520 + l4 * 8];
      f32x4 a0 = {0.f, 0.f, 0.f, 0.f}, a1 = {0.f, 0.f, 0.f, 0.f};
#pragma unroll
      for (int kk = 0; kk < 16; kk += 2) {
        a0 = __builtin_amdgcn_mfma_f32_16x16x32_bf16(*(const bf16x8*)(ap + kk * 32), UB[kk], a0, 0, 0, 0);
        a1 = __builtin_amdgcn_mfma_f32_16x16x32_bf16(*(const bf16x8*)(ap + kk * 32 + 32), UB[kk + 1], a1, 0, 0, 0);
      }
      const f32x4 acc = a0 + a1;
      const int lc = p1nt * 16 + l15;
#pragma unroll
      for (int q = 0; q < 4; ++q) {
        const int row = l4 * 4 + q;
        const float pre = acc[q] + bfu2f(c1u[q]);
        const float s = 1.f / (1.f + __expf(-pre));
        if (p1gate == 0) z_sh[row * 32 + lc] = s;
        else rh_buf[((g * 16 + row) << 9) + j * 32 + lc] = f2bf(s * hown[row * 32 + lc]);
      }
    }
    if (group_barrier(ctr, (++nbar) * 16, tid, &s_dead)) break;

    // ---- phase 2: h~ from (r*h), h update
    stage16x512(rh_buf, g, h_st, tid);
    __syncthreads();
    {
      const ushort_t* ap = &h_st[l15 * 520 + p2kh * 256 + l4 * 8];
      f32x4 a0 = {0.f, 0.f, 0.f, 0.f}, a1 = {0.f, 0.f, 0.f, 0.f};
#pragma unroll
      for (int kk = 0; kk < 8; kk += 2) {
        a0 = __builtin_amdgcn_mfma_f32_16x16x32_bf16(*(const bf16x8*)(ap + kk * 32), UH[kk], a0, 0, 0, 0);
        a1 = __builtin_amdgcn_mfma_f32_16x16x32_bf16(*(const bf16x8*)(ap + kk * 32 + 32), UH[kk + 1], a1, 0, 0, 0);
      }
      const f32x4 acc = a0 + a1;
      if (p2kh == 1) {
#pragma unroll
        for (int q = 0; q < 4; ++q) red[p2nt * 256 + (l4 * 4 + q) * 16 + l15] = acc[q];
      }
      __syncthreads();
      if (p2kh == 0) {
        const int lc = p2nt * 16 + l15;
#pragma unroll
        for (int q = 0; q < 4; ++q) {
          const int row = l4 * 4 + q;
          const float dot = acc[q] + red[p2nt * 256 + row * 16 + l15];
          float pre = dot + bfu2f(c2u[q]);
          pre = fminf(15.f, fmaxf(-15.f, pre));
          const float e = __expf(2.f * pre);
          const float th = (e - 1.f) / (e + 1.f);
          const float z = z_sh[row * 32 + lc];
          const float hold = hown[row * 32 + lc];
          const float hnew = (1.f - z) * hold + z * th;
          hown[row * 32 + lc] = hnew;
          h_buf[((g * 16 + row) << 9) + j * 32 + lc] = f2bf(hnew);
          if (tt == Tc - 1) h_state[((g * 16 + row) << 9) + j * 32 + lc] = hnew;
        }
      }
    }

    // ---- barrier 2 with embedded next-step gate prefetch:
    // stores committed FIRST, then raw loads issued -> they fly across the poll
    // and the next stage; first safe consumption is after stage's vmcnt(0).
    asm volatile("s_waitcnt vmcnt(0)" ::: "memory");
    if (tt + 1 < Tc) {
      const size_t gb = (size_t)((size_t)(tt + 1) * 256 + g * 16) * 1536;
      const ushort_t* b1  = &gates[gb + (size_t)(l4 * 4) * 1536 + (p1gate << 9) + colg1];
      const ushort_t* b1c = b1 + 2 * 1536;
      const ushort_t* b2  = &gates[gb + (size_t)(l4 * 4) * 1536 + 1024 + colg2];
      const ushort_t* b2c = b2 + 2 * 1536;
      GLOAD_U16(n1u[0], b1, 0);   GLOAD_U16(n1u[1], b1, 3072);
      GLOAD_U16(n1u[2], b1c, 0);  GLOAD_U16(n1u[3], b1c, 3072);
      GLOAD_U16(n2u[0], b2, 0);   GLOAD_U16(n2u[1], b2, 3072);
      GLOAD_U16(n2u[2], b2c, 0);  GLOAD_U16(n2u[3], b2c, 3072);
    }
    __syncthreads();
    if (tid == 0) {
      atom_add_noret(ctr, 1u);
      const uint_t target = (++nbar) * 16;
      int cnt = 0;
      for (;;) {
        const uint_t seen = atom_add_ret(ctr, 0u);
        if (seen >= target) break;
        __builtin_amdgcn_s_sleep(1);
        if (++cnt > (1 << 15)) { s_dead = 1; break; }
      }
    } else {
      ++nbar;
    }
    __syncthreads();
    if (s_dead) break;
  }
}

// ---------------------------------------------------------------- FC: logits = relu(h) @ Wfc + bfc
__global__ __launch_bounds__(256) void fc_kernel(
    const float* __restrict__ h, const float* __restrict__ Wfc,
    const float* __restrict__ bfc, float* __restrict__ logits)
{
  __shared__ float hsh[16][520];
  const int tid = threadIdx.x;
  const int by = blockIdx.y;
  {
    const int r = tid >> 4, seg = tid & 15;
    const float* src = &h[(size_t)(by * 16 + r) * 512 + seg * 32];
#pragma unroll
    for (int i = 0; i < 8; ++i) {
      float4 v = *(const float4*)&src[i * 4];
      v.x = fmaxf(v.x, 0.f); v.y = fmaxf(v.y, 0.f);
      v.z = fmaxf(v.z, 0.f); v.w = fmaxf(v.w, 0.f);
      *(float4*)&hsh[r][seg * 32 + i * 4] = v;
    }
  }
  __syncthreads();
  const int c = tid & 63, rq = tid >> 6;
  const int gc = blockIdx.x * 64 + c;
  if (gc >= 1000) return;
  float acc0 = 0.f, acc1 = 0.f, acc2 = 0.f, acc3 = 0.f;
  for (int k = 0; k < 512; ++k) {
    const float w = Wfc[(size_t)k * 1000 + gc];
    acc0 += hsh[rq * 4 + 0][k] * w;
    acc1 += hsh[rq * 4 + 1][k] * w;
    acc2 += hsh[rq * 4 + 2][k] * w;
    acc3 += hsh[rq * 4 + 3][k] * w;
  }
  const float bv = bfc[gc];
  const int r0 = by * 16 + rq * 4;
  logits[(size_t)(r0 + 0) * 1000 + gc] = acc0 + bv;
  logits[(size_t)(r0 + 1) * 1000 + gc] = acc1 + bv;
  logits[(size_t)(r0 + 2) * 1000 + gc] = acc2 + bv;
  logits[(size_t)(r0 + 3) * 1000 + gc] = acc3 + bv;
}

// ---------------------------------------------------------------- log_softmax over batch axis
__global__ __launch_bounds__(256) void lsm_kernel(const float* __restrict__ logits,
                                                  float* __restrict__ out)
{
  const int c = blockIdx.x, tid = threadIdx.x;
  const int wid = tid >> 6, lane = tid & 63;
  __shared__ float red[8];
  const float v = logits[(size_t)tid * 1000 + c];
  float m = v;
#pragma unroll
  for (int o = 32; o >= 1; o >>= 1) m = fmaxf(m, __shfl_xor(m, o));
  if (lane == 0) red[wid] = m;
  __syncthreads();
  m = fmaxf(fmaxf(red[0], red[1]), fmaxf(red[2], red[3]));
  float s = __expf(v - m);
#pragma unroll
  for (int o = 32; o >= 1; o >>= 1) s += __shfl_xor(s, o);
  if (lane == 0) red[4 + wid] = s;
  __syncthreads();
  s = red[4] + red[5] + red[6] + red[7];
  out[(size_t)tid * 1000 + c] = (v - m) - __logf(s);
}

// ---------------------------------------------------------------- launch
extern "C" void kernel_launch(void* const* d_in, const int* in_sizes, int n_in,
                              void* d_out, int out_size, void* d_ws, size_t ws_size,
                              hipStream_t stream) {
  (void)in_sizes; (void)n_in; (void)out_size;
  const float* x   = (const float*)d_in[0];
  const float* Wz  = (const float*)d_in[1];
  const float* bz  = (const float*)d_in[2];
  const float* Uz  = (const float*)d_in[3];
  const float* buz = (const float*)d_in[4];
  const float* Wr  = (const float*)d_in[5];
  const float* br  = (const float*)d_in[6];
  const float* Ur  = (const float*)d_in[7];
  const float* bur = (const float*)d_in[8];
  const float* Wh  = (const float*)d_in[9];
  const float* bh  = (const float*)d_in[10];
  const float* Uh  = (const float*)d_in[11];
  const float* buh = (const float*)d_in[12];
  const float* Wfc = (const float*)d_in[13];
  const float* bfc = (const float*)d_in[14];
  float* out = (float*)d_out;
  char* ws = (char*)d_ws;

  ushort_t* UT     = (ushort_t*)(ws + 0);        // 1572864 B
  ushort_t* WT     = (ushort_t*)(ws + 1572864);  // 1572864 B
  float*    gbias  = (float*)(ws + 3145728);     // 6144 B
  ushort_t* h_buf  = (ushort_t*)(ws + 3151872);  // 262144 B
  ushort_t* rh_buf = (ushort_t*)(ws + 3414016);  // 262144 B
  float*    hstate = (float*)(ws + 3676160);     // 524288 B
  float*    logits = (float*)(ws + 4200448);     // 1024000 B (256x1000)
  uint_t*   bars   = (uint_t*)(ws + 5224448);    // 4096 B (16 groups x 256B)
  ushort_t* gates  = (ushort_t*)(ws + 5228544);  // Tc*256*1536*2 B

  const size_t fixed = 5228544;
  const size_t per_step = (size_t)256 * 1536 * 2;
  int Tc_max = 2048;
  if (ws_size < fixed + (size_t)2048 * per_step) {
    const size_t avail = (ws_size > fixed) ? (ws_size - fixed) : 0;
    Tc_max = (int)(avail / per_step);
    Tc_max &= ~15;             // keep mtiles % 32 == 0 for the GEMM supertile swizzle
    if (Tc_max < 16) Tc_max = 16;
  }

  prep_kernel<<<3072, 256, 0, stream>>>(Wz, Wr, Wh, Uz, Ur, Uh,
                                        bz, buz, br, bur, bh, buh, UT, WT, gbias);

  int done = 0;
  while (done < 2048) {
    const int Tc = (2048 - done < Tc_max) ? (2048 - done) : Tc_max;
    const int mtiles = Tc * 2;  // Tc*256/128
    gate_gemm<<<mtiles * 12, 256, 0, stream>>>(x + (size_t)done * 256 * 512, WT, gbias, gates, mtiles);
    hipMemsetAsync(bars, 0, 4096, stream);
    gru_rec<<<256, 256, 0, stream>>>(UT, gates, h_buf, rh_buf, hstate, bars, Tc, done == 0 ? 1 : 0);
    done += Tc;
  }
  fc_kernel<<<dim3(16, 16), 256, 0, stream>>>(hstate, Wfc, bfc, logits);
  lsm_kernel<<<1000, 256, 0, stream>>>(logits, out);
}

// Round 7
// 9938.943 us; speedup vs baseline: 7.5945x; 1.0018x over previous
//
#include <hip/hip_runtime.h>

// CustomRNN (GRU, SEQ=2048, B=256, D=512) + FC(1000) + log_softmax over batch axis.
//
// RE-ANCHOR: byte-exact resubmission of the last PASSING kernel (R3, 9.96 ms).
// Six-round bisect conclusion: inter-block sync must stay in ATOMIC-RMW class
// (arrival = global_atomic_add, poll = global_atomic_add 0 at the TCC). Every
// variant polling with plain sc0 loads failed with identical absmax 0.40625.
//
//   gru_rec: persistent, 256 blocks = 16 groups x 16 col-slice blocks.
//   Sync is XCD-local TCC atomics; h/rh exchanged through the shared per-XCD L2.
//   Gate loads for step t+1 issued as raw asm loads AFTER the store-drain of step
//   t's last barrier; consumed only after the next stage's vmcnt(0).

typedef unsigned short ushort_t;
typedef unsigned int uint_t;
typedef __bf16 bf16_t;
typedef bf16_t bf16x8 __attribute__((ext_vector_type(8)));
typedef float f32x4 __attribute__((ext_vector_type(4)));
typedef uint_t u32x4 __attribute__((ext_vector_type(4)));

__device__ __forceinline__ ushort_t f2bf(float f) {
  uint_t u = __float_as_uint(f);
  u += 0x7FFFu + ((u >> 16) & 1u);   // round-to-nearest-even
  return (ushort_t)(u >> 16);
}
__device__ __forceinline__ float bfu2f(uint_t h) { return __uint_as_float(h << 16); }

// TCC-local atomic add WITH return (waits). Used for polling (RMW -> always
// served coherently at the TCC; plain sc0 loads are NOT sufficient - R4/R5/R6).
__device__ __forceinline__ uint_t atom_add_ret(uint_t* p, uint_t v) {
  uint_t old;
  asm volatile("global_atomic_add %0, %1, %2, off sc0\n\t"
               "s_waitcnt vmcnt(0)"
               : "=v"(old) : "v"(p), "v"(v) : "memory");
  return old;
}
// Fire-and-forget atomic add (no return -> no wait).
__device__ __forceinline__ void atom_add_noret(uint_t* p, uint_t v) {
  asm volatile("global_atomic_add %0, %1, off" :: "v"(p), "v"(v) : "memory");
}

// Raw u16 load: issues immediately, NO compiler-tracked wait. Value is only
// safe to read after a subsequent s_waitcnt vmcnt(0) (stage16x512 provides it).
#define GLOAD_U16(dst, ptr, off) \
  asm volatile("global_load_ushort %0, %1, off offset:" #off : "=v"(dst) : "v"(ptr))

// ---------------------------------------------------------------- prep
__global__ __launch_bounds__(256) void prep_kernel(
    const float* __restrict__ Wz, const float* __restrict__ Wr, const float* __restrict__ Wh,
    const float* __restrict__ Uz, const float* __restrict__ Ur, const float* __restrict__ Uh,
    const float* __restrict__ bz, const float* __restrict__ buz,
    const float* __restrict__ br, const float* __restrict__ bur,
    const float* __restrict__ bh, const float* __restrict__ buh,
    ushort_t* __restrict__ UT, ushort_t* __restrict__ WT, float* __restrict__ gbias)
{
  const int idx = blockIdx.x * 256 + threadIdx.x;  // exactly 786432 threads
  {
    const int gate = idx >> 18, n = (idx >> 9) & 511, k = idx & 511;
    const float* U = (gate == 0) ? Uz : (gate == 1 ? Ur : Uh);
    UT[idx] = f2bf(U[k * 512 + n]);                 // UT[gate][n][k] = U[k][n]
  }
  {
    const int n = idx >> 9, k = idx & 511;
    const int gate = n >> 9, nn = n & 511;
    const float* W = (gate == 0) ? Wz : (gate == 1 ? Wr : Wh);
    WT[idx] = f2bf(W[k * 512 + nn]);                // WT[n][k] = W[k][n]
  }
  if (idx < 1536) {
    const int gate = idx >> 9, nn = idx & 511;
    gbias[idx] = (gate == 0) ? (bz[nn] + buz[nn])
               : (gate == 1) ? (br[nn] + bur[nn])
                             : (bh[nn] + buh[nn]);
  }
}

// ---------------------------------------------------------------- gate GEMM
__global__ __launch_bounds__(256) void gate_gemm(
    const float* __restrict__ x,
    const ushort_t* __restrict__ WT,     // [1536][512] (n-major)
    const float* __restrict__ gbias,
    ushort_t* __restrict__ gout,         // [M][1536]
    int mtiles)
{
  __shared__ ushort_t A_sh[128 * 72];
  __shared__ ushort_t B_sh[128 * 72];
  const int bid = blockIdx.x;
  int mt, nt;
  if ((mtiles & 31) == 0) {              // supertile 32 mtiles x 12 ntiles for A L2/L3 reuse
    const int sb = bid / 384;
    const int r = bid - sb * 384;
    mt = sb * 32 + (r & 31);
    nt = r >> 5;
  } else {
    mt = bid / 12;
    nt = bid - mt * 12;
  }
  const int mrow0 = mt * 128;
  const int ncol0 = nt * 128;
  const int tid = threadIdx.x;
  const int wid = tid >> 6;
  const int lane = tid & 63;
  const int wm = wid >> 1, wn = wid & 1;
  const int l15 = lane & 15, l4 = lane >> 4;

  const f32x4 vzero = {0.f, 0.f, 0.f, 0.f};
  f32x4 acc[4][4];
#pragma unroll
  for (int m = 0; m < 4; ++m)
#pragma unroll
    for (int n = 0; n < 4; ++n) acc[m][n] = vzero;

  const int ar = tid >> 4, ak = tid & 15;
  const int bn = tid >> 3, bk = tid & 7;

  for (int ks = 0; ks < 8; ++ks) {
    if (ks) __syncthreads();
    const int k0 = ks * 64;
#pragma unroll
    for (int p = 0; p < 8; ++p) {
      const int r = p * 16 + ar;
      const float4 v = *(const float4*)&x[(size_t)(mrow0 + r) * 512 + (k0 + ak * 4)];
      ushort4 hv;
      hv.x = f2bf(v.x); hv.y = f2bf(v.y); hv.z = f2bf(v.z); hv.w = f2bf(v.w);
      *(ushort4*)&A_sh[r * 72 + ak * 4] = hv;
    }
#pragma unroll
    for (int p = 0; p < 4; ++p) {
      const int n = p * 32 + bn;
      *(uint4*)&B_sh[n * 72 + bk * 8] =
          *(const uint4*)&WT[(size_t)(ncol0 + n) * 512 + (k0 + bk * 8)];
    }
    __syncthreads();
#pragma unroll
    for (int kk = 0; kk < 2; ++kk) {
      bf16x8 a[4], b[4];
#pragma unroll
      for (int m = 0; m < 4; ++m)
        a[m] = *(const bf16x8*)&A_sh[(wm * 64 + m * 16 + l15) * 72 + kk * 32 + l4 * 8];
#pragma unroll
      for (int n = 0; n < 4; ++n)
        b[n] = *(const bf16x8*)&B_sh[(wn * 64 + n * 16 + l15) * 72 + kk * 32 + l4 * 8];
#pragma unroll
      for (int m = 0; m < 4; ++m)
#pragma unroll
        for (int n = 0; n < 4; ++n)
          acc[m][n] = __builtin_amdgcn_mfma_f32_16x16x32_bf16(a[m], b[n], acc[m][n], 0, 0, 0);
    }
  }
#pragma unroll
  for (int n = 0; n < 4; ++n) {
    const int gcol = ncol0 + wn * 64 + n * 16 + l15;
    const float bv = gbias[gcol];
#pragma unroll
    for (int m = 0; m < 4; ++m) {
      const int grow = mrow0 + wm * 64 + m * 16 + l4 * 4;
#pragma unroll
      for (int q = 0; q < 4; ++q)
        gout[(size_t)(grow + q) * 1536 + gcol] = f2bf(acc[m][n][q] + bv);
    }
  }
}

// ---------------------------------------------------------------- XCD-local group barrier
// Monotone counter; arrival = non-blocking add, wait = poll RMW until ctr >= 16*n.
__device__ __forceinline__ bool group_barrier(uint_t* ctr, uint_t target, int tid, int* s_dead) {
  asm volatile("s_waitcnt vmcnt(0)" ::: "memory");  // own stores committed to L2
  __syncthreads();                                   // all waves drained
  if (tid == 0) {
    atom_add_noret(ctr, 1u);
    int cnt = 0;
    for (;;) {
      const uint_t seen = atom_add_ret(ctr, 0u);     // RMW -> always served at TCC
      if (seen >= target) break;
      __builtin_amdgcn_s_sleep(1);
      if (++cnt > (1 << 15)) { *s_dead = 1; break; } // co-location broken: fast-fail
    }
  }
  __syncthreads();
  return *s_dead != 0;
}

// Stage a [16 rows][512] bf16 tile (16 KB) from global (shared L2) into LDS.
// sc0 loads bypass the (possibly stale) L1; ends with vmcnt(0) -> also the
// safety point for any raw GLOAD_U16 issued earlier.
__device__ __forceinline__ void stage16x512(const ushort_t* __restrict__ src, int g,
                                            ushort_t* dst_lds, int tid) {
  const ushort_t* p[4];
#pragma unroll
  for (int k = 0; k < 4; ++k) {
    const int idx = tid + (k << 8);
    const int r = idx >> 6, kc = idx & 63;
    p[k] = src + (((g * 16 + r) << 9) + kc * 8);
  }
  u32x4 v0, v1, v2, v3;
  asm volatile(
      "global_load_dwordx4 %0, %4, off sc0\n\t"
      "global_load_dwordx4 %1, %5, off sc0\n\t"
      "global_load_dwordx4 %2, %6, off sc0\n\t"
      "global_load_dwordx4 %3, %7, off sc0\n\t"
      "s_waitcnt vmcnt(0)"
      : "=&v"(v0), "=&v"(v1), "=&v"(v2), "=&v"(v3)
      : "v"(p[0]), "v"(p[1]), "v"(p[2]), "v"(p[3])
      : "memory");
#pragma unroll
  for (int k = 0; k < 4; ++k) {
    const int idx = tid + (k << 8);
    const int r = idx >> 6, kc = idx & 63;
    *(u32x4*)&dst_lds[r * 520 + kc * 8] = (k == 0) ? v0 : (k == 1) ? v1 : (k == 2) ? v2 : v3;
  }
}

// ---------------------------------------------------------------- persistent GRU recurrence
__global__ __launch_bounds__(256, 1) void gru_rec(
    const ushort_t* __restrict__ UT,     // [3][512 n][512 k] bf16
    const ushort_t* __restrict__ gates,  // [Tc][256][1536] bf16
    ushort_t* __restrict__ h_buf,        // [256][512] bf16
    ushort_t* __restrict__ rh_buf,       // [256][512] bf16
    float* __restrict__ h_state,         // [256][512] fp32
    uint_t* __restrict__ bars,
    int Tc, int first)
{
  __shared__ ushort_t h_st[16 * 520];
  __shared__ float z_sh[512];
  __shared__ float hown[512];
  __shared__ float red[512];
  __shared__ int s_dead;

  const int tid = threadIdx.x;
  const int bid = blockIdx.x;
  const int g = bid & 15;
  const int j = bid >> 4;
  const int wid = tid >> 6;
  const int lane = tid & 63;
  const int l15 = lane & 15;
  const int l4 = lane >> 4;
  if (tid == 0) s_dead = 0;

  uint_t* ctr = bars + g * 64;          // one counter per group, own cacheline
  uint_t nbar = 0;

  const int p1gate = wid >> 1;  // phase1: waves 0,1 -> z ; waves 2,3 -> r
  const int p1nt = wid & 1;
  const int p2nt = wid >> 1;    // phase2 subtile
  const int p2kh = wid & 1;     // phase2 K half

  // U fragments persistent in registers
  bf16x8 UB[16];
  {
    const size_t base = (size_t)((p1gate << 9) + j * 32 + p1nt * 16 + l15) * 512 + (size_t)(l4 * 8);
#pragma unroll
    for (int kk = 0; kk < 16; ++kk) UB[kk] = *(const bf16x8*)&UT[base + (size_t)kk * 32];
  }
  bf16x8 UH[8];
  {
    const size_t base = (size_t)(1024 + j * 32 + p2nt * 16 + l15) * 512 + (size_t)(p2kh * 256 + l4 * 8);
#pragma unroll
    for (int kk = 0; kk < 8; ++kk) UH[kk] = *(const bf16x8*)&UT[base + (size_t)kk * 32];
  }

  if (first) {
    for (int i = tid; i < 512; i += 256) {
      const int r = i >> 5, c = i & 31;
      h_buf[((g * 16 + r) << 9) + j * 32 + c] = 0;
      hown[i] = 0.f;
    }
  } else {
    for (int i = tid; i < 512; i += 256) {
      const int r = i >> 5, c = i & 31;
      hown[i] = h_state[((g * 16 + r) << 9) + j * 32 + c];
    }
  }
  if (group_barrier(ctr, (++nbar) * 16, tid, &s_dead)) return;

  const int colg1 = j * 32 + p1nt * 16 + l15;
  const int colg2 = j * 32 + p2nt * 16 + l15;

  // gate pipeline registers: n* loaded (possibly via raw asm) for step tt,
  // copied to c* only after a vmcnt(0) drain (stage16x512) -> hardware-safe.
  uint_t c1u[4], c2u[4], n1u[4], n2u[4];
  {
    const size_t gb = (size_t)(g * 16) * 1536;
#pragma unroll
    for (int q = 0; q < 4; ++q) {
      n1u[q] = gates[gb + (size_t)(l4 * 4 + q) * 1536 + (p1gate << 9) + colg1];
      n2u[q] = gates[gb + (size_t)(l4 * 4 + q) * 1536 + 1024 + colg2];
    }
  }

  for (int tt = 0; tt < Tc; ++tt) {
    // ---- phase 1: z, r from h
    stage16x512(h_buf, g, h_st, tid);      // ends vmcnt(0): n1u/n2u now valid
    __syncthreads();
#pragma unroll
    for (int q = 0; q < 4; ++q) { c1u[q] = n1u[q]; c2u[q] = n2u[q]; }
    {
      const ushort_t* ap = &h_st[l15 * 520 + l4 * 8];
      f32x4 a0 = {0.f, 0.f, 0.f, 0.f}, a1 = {0.f, 0.f, 0.f, 0.f};
#pragma unroll
      for (int kk = 0; kk < 16; kk += 2) {
        a0 = __builtin_amdgcn_mfma_f32_16x16x32_bf16(*(const bf16x8*)(ap + kk * 32), UB[kk], a0, 0, 0, 0);
        a1 = __builtin_amdgcn_mfma_f32_16x16x32_bf16(*(const bf16x8*)(ap + kk * 32 + 32), UB[kk + 1], a1, 0, 0, 0);
      }
      const f32x4 acc = a0 + a1;
      const int lc = p1nt * 16 + l15;
#pragma unroll
      for (int q = 0; q < 4; ++q) {
        const int row = l4 * 4 + q;
        const float pre = acc[q] + bfu2f(c1u[q]);
        const float s = 1.f / (1.f + __expf(-pre));
        if (p1gate == 0) z_sh[row * 32 + lc] = s;
        else rh_buf[((g * 16 + row) << 9) + j * 32 + lc] = f2bf(s * hown[row * 32 + lc]);
      }
    }
    if (group_barrier(ctr, (++nbar) * 16, tid, &s_dead)) break;

    // ---- phase 2: h~ from (r*h), h update
    stage16x512(rh_buf, g, h_st, tid);
    __syncthreads();
    {
      const ushort_t* ap = &h_st[l15 * 520 + p2kh * 256 + l4 * 8];
      f32x4 a0 = {0.f, 0.f, 0.f, 0.f}, a1 = {0.f, 0.f, 0.f, 0.f};
#pragma unroll
      for (int kk = 0; kk < 8; kk += 2) {
        a0 = __builtin_amdgcn_mfma_f32_16x16x32_bf16(*(const bf16x8*)(ap + kk * 32), UH[kk], a0, 0, 0, 0);
        a1 = __builtin_amdgcn_mfma_f32_16x16x32_bf16(*(const bf16x8*)(ap + kk * 32 + 32), UH[kk + 1], a1, 0, 0, 0);
      }
      const f32x4 acc = a0 + a1;
      if (p2kh == 1) {
#pragma unroll
        for (int q = 0; q < 4; ++q) red[p2nt * 256 + (l4 * 4 + q) * 16 + l15] = acc[q];
      }
      __syncthreads();
      if (p2kh == 0) {
        const int lc = p2nt * 16 + l15;
#pragma unroll
        for (int q = 0; q < 4; ++q) {
          const int row = l4 * 4 + q;
          const float dot = acc[q] + red[p2nt * 256 + row * 16 + l15];
          float pre = dot + bfu2f(c2u[q]);
          pre = fminf(15.f, fmaxf(-15.f, pre));
          const float e = __expf(2.f * pre);
          const float th = (e - 1.f) / (e + 1.f);
          const float z = z_sh[row * 32 + lc];
          const float hold = hown[row * 32 + lc];
          const float hnew = (1.f - z) * hold + z * th;
          hown[row * 32 + lc] = hnew;
          h_buf[((g * 16 + row) << 9) + j * 32 + lc] = f2bf(hnew);
          if (tt == Tc - 1) h_state[((g * 16 + row) << 9) + j * 32 + lc] = hnew;
        }
      }
    }

    // ---- barrier 2 with embedded next-step gate prefetch:
    // stores committed FIRST, then raw loads issued -> they fly across the poll
    // and the next stage; first safe consumption is after stage's vmcnt(0).
    asm volatile("s_waitcnt vmcnt(0)" ::: "memory");
    if (tt + 1 < Tc) {
      const size_t gb = (size_t)((size_t)(tt + 1) * 256 + g * 16) * 1536;
      const ushort_t* b1  = &gates[gb + (size_t)(l4 * 4) * 1536 + (p1gate << 9) + colg1];
      const ushort_t* b1c = b1 + 2 * 1536;
      const ushort_t* b2  = &gates[gb + (size_t)(l4 * 4) * 1536 + 1024 + colg2];
      const ushort_t* b2c = b2 + 2 * 1536;
      GLOAD_U16(n1u[0], b1, 0);   GLOAD_U16(n1u[1], b1, 3072);
      GLOAD_U16(n1u[2], b1c, 0);  GLOAD_U16(n1u[3], b1c, 3072);
      GLOAD_U16(n2u[0], b2, 0);   GLOAD_U16(n2u[1], b2, 3072);
      GLOAD_U16(n2u[2], b2c, 0);  GLOAD_U16(n2u[3], b2c, 3072);
    }
    __syncthreads();
    if (tid == 0) {
      atom_add_noret(ctr, 1u);
      const uint_t target = (++nbar) * 16;
      int cnt = 0;
      for (;;) {
        const uint_t seen = atom_add_ret(ctr, 0u);
        if (seen >= target) break;
        __builtin_amdgcn_s_sleep(1);
        if (++cnt > (1 << 15)) { s_dead = 1; break; }
      }
    } else {
      ++nbar;
    }
    __syncthreads();
    if (s_dead) break;
  }
}

// ---------------------------------------------------------------- FC
__global__ __launch_bounds__(256) void fc_kernel(
    const float* __restrict__ h, const float* __restrict__ Wfc,
    const float* __restrict__ bfc, float* __restrict__ logits)
{
  __shared__ float hsh[16][520];
  const int tid = threadIdx.x;
  const int by = blockIdx.y;
  {
    const int r = tid >> 4, seg = tid & 15;
    const float* src = &h[(size_t)(by * 16 + r) * 512 + seg * 32];
#pragma unroll
    for (int i = 0; i < 8; ++i) {
      float4 v = *(const float4*)&src[i * 4];
      v.x = fmaxf(v.x, 0.f); v.y = fmaxf(v.y, 0.f);
      v.z = fmaxf(v.z, 0.f); v.w = fmaxf(v.w, 0.f);
      *(float4*)&hsh[r][seg * 32 + i * 4] = v;
    }
  }
  __syncthreads();
  const int c = tid & 63, rq = tid >> 6;
  const int gc = blockIdx.x * 64 + c;
  if (gc >= 1000) return;
  float acc0 = 0.f, acc1 = 0.f, acc2 = 0.f, acc3 = 0.f;
  for (int k = 0; k < 512; ++k) {
    const float w = Wfc[(size_t)k * 1000 + gc];
    acc0 += hsh[rq * 4 + 0][k] * w;
    acc1 += hsh[rq * 4 + 1][k] * w;
    acc2 += hsh[rq * 4 + 2][k] * w;
    acc3 += hsh[rq * 4 + 3][k] * w;
  }
  const float bv = bfc[gc];
  const int r0 = by * 16 + rq * 4;
  logits[(size_t)(r0 + 0) * 1000 + gc] = acc0 + bv;
  logits[(size_t)(r0 + 1) * 1000 + gc] = acc1 + bv;
  logits[(size_t)(r0 + 2) * 1000 + gc] = acc2 + bv;
  logits[(size_t)(r0 + 3) * 1000 + gc] = acc3 + bv;
}

// ---------------------------------------------------------------- log_softmax over batch
__global__ __launch_bounds__(256) void lsm_kernel(const float* __restrict__ logits,
                                                  float* __restrict__ out)
{
  const int c = blockIdx.x, tid = threadIdx.x;
  const int wid = tid >> 6, lane = tid & 63;
  __shared__ float red[8];
  const float v = logits[(size_t)tid * 1000 + c];
  float m = v;
#pragma unroll
  for (int o = 32; o >= 1; o >>= 1) m = fmaxf(m, __shfl_xor(m, o));
  if (lane == 0) red[wid] = m;
  __syncthreads();
  m = fmaxf(fmaxf(red[0], red[1]), fmaxf(red[2], red[3]));
  float s = __expf(v - m);
#pragma unroll
  for (int o = 32; o >= 1; o >>= 1) s += __shfl_xor(s, o);
  if (lane == 0) red[4 + wid] = s;
  __syncthreads();
  s = red[4] + red[5] + red[6] + red[7];
  out[(size_t)tid * 1000 + c] = (v - m) - __logf(s);
}

// ---------------------------------------------------------------- launch
extern "C" void kernel_launch(void* const* d_in, const int* in_sizes, int n_in,
                              void* d_out, int out_size, void* d_ws, size_t ws_size,
                              hipStream_t stream) {
  (void)in_sizes; (void)n_in; (void)out_size;
  const float* x   = (const float*)d_in[0];
  const float* Wz  = (const float*)d_in[1];
  const float* bz  = (const float*)d_in[2];
  const float* Uz  = (const float*)d_in[3];
  const float* buz = (const float*)d_in[4];
  const float* Wr  = (const float*)d_in[5];
  const float* br  = (const float*)d_in[6];
  const float* Ur  = (const float*)d_in[7];
  const float* bur = (const float*)d_in[8];
  const float* Wh  = (const float*)d_in[9];
  const float* bh  = (const float*)d_in[10];
  const float* Uh  = (const float*)d_in[11];
  const float* buh = (const float*)d_in[12];
  const float* Wfc = (const float*)d_in[13];
  const float* bfc = (const float*)d_in[14];
  float* out = (float*)d_out;
  char* ws = (char*)d_ws;

  ushort_t* UT     = (ushort_t*)(ws + 0);        // 1572864 B
  ushort_t* WT     = (ushort_t*)(ws + 1572864);  // 1572864 B
  float*    gbias  = (float*)(ws + 3145728);     // 6144 B
  ushort_t* h_buf  = (ushort_t*)(ws + 3151872);  // 262144 B
  ushort_t* rh_buf = (ushort_t*)(ws + 3414016);  // 262144 B
  float*    hstate = (float*)(ws + 3676160);     // 524288 B
  float*    logits = (float*)(ws + 4200448);     // 1024000 B (256x1000)
  uint_t*   bars   = (uint_t*)(ws + 5224448);    // 4096 B (16 groups x 256B)
  ushort_t* gates  = (ushort_t*)(ws + 5228544);  // Tc*256*1536*2 B

  const size_t fixed = 5228544;
  const size_t per_step = (size_t)256 * 1536 * 2;
  int Tc_max = 2048;
  if (ws_size < fixed + (size_t)2048 * per_step) {
    const size_t avail = (ws_size > fixed) ? (ws_size - fixed) : 0;
    Tc_max = (int)(avail / per_step);
    Tc_max &= ~15;             // keep mtiles % 32 == 0 for the GEMM supertile swizzle
    if (Tc_max < 16) Tc_max = 16;
  }

  prep_kernel<<<3072, 256, 0, stream>>>(Wz, Wr, Wh, Uz, Ur, Uh,
                                        bz, buz, br, bur, bh, buh, UT, WT, gbias);

  int done = 0;
  while (done < 2048) {
    const int Tc = (2048 - done < Tc_max) ? (2048 - done) : Tc_max;
    const int mtiles = Tc * 2;  // Tc*256/128
    gate_gemm<<<mtiles * 12, 256, 0, stream>>>(x + (size_t)done * 256 * 512, WT, gbias, gates, mtiles);
    hipMemsetAsync(bars, 0, 4096, stream);
    gru_rec<<<256, 256, 0, stream>>>(UT, gates, h_buf, rh_buf, hstate, bars, Tc, done == 0 ? 1 : 0);
    done += Tc;
  }
  fc_kernel<<<dim3(16, 16), 256, 0, stream>>>(hstate, Wfc, bfc, logits);
  lsm_kernel<<<1000, 256, 0, stream>>>(logits, out);
}